// Round 9
// baseline (355.397 us; speedup 1.0000x reference)
//
#include <hip/hip_runtime.h>
#include <math.h>

typedef short short8 __attribute__((ext_vector_type(8)));
typedef float f32x4 __attribute__((ext_vector_type(4)));
typedef unsigned short u16;
typedef unsigned int u32;

#define S_TOK 4096
#define DM 768
#define DF 3072
#define NE 8
#define NSLOT (S_TOK*2)      // 8192 real slots
#define PSLOT 9216           // padded capacity (8192 + 8*127 rounded up)
#define MBMAX 72             // PSLOT/128

// ---- control block ----
// counts/cursor are cacheline-padded: expert e lives at [e*16] (64 B stride)
#define WS_COUNTS   0        // 128 ints (8 x 16-int stride)
#define WS_CURSOR   512      // 128 ints (zero-based rank cursor)
#define WS_EID      2048     // NSLOT ints
#define WS_GW       (WS_EID + NSLOT*4)
#define WS_POS      (WS_GW  + NSLOT*4)      // NSLOT ints: slot position of (token,k)
#define WS_TOK      (WS_POS + NSLOT*4)      // PSLOT ints
#define CTRL_BYTES  262144

#define AS1 __attribute__((address_space(1)))
#define AS3 __attribute__((address_space(3)))
#define GLDS16(g, s) __builtin_amdgcn_global_load_lds((const AS1 u32*)(g), (AS3 u32*)(s), 16, 0, 0)

__device__ inline u16 f2b(float f){
    u32 u = __builtin_bit_cast(u32, f);
    u32 r = (u + 0x7fffu + ((u >> 16) & 1u)) >> 16;   // RNE
    return (u16)r;
}

// expert region search over padded counts: returns -1 if row m0base is beyond total
__device__ inline int expert_of_row(const int* __restrict__ counts, int m0base){
    int e = -1, P = 0;
#pragma unroll
    for (int q = 0; q < NE; q++){
        int padded = ((counts[q*16] + 127) >> 7) << 7;
        if (m0base >= P && m0base < P + padded) e = q;
        P += padded;
    }
    return e;
}

// ---------------- W fp32 [e][K][N] -> bf16 fragment order, direct gather (no LDS) ----------------
__global__ __launch_bounds__(256) void cvtw_kernel(const float* __restrict__ W1, u16* __restrict__ W1s,
                                                   const float* __restrict__ W2, u16* __restrict__ W2s,
                                                   int* __restrict__ counts, int* __restrict__ cursor){
    if (blockIdx.x == 0 && blockIdx.y == 0 && threadIdx.x < 128){
        counts[threadIdx.x] = 0; cursor[threadIdx.x] = 0;
    }
    int e = blockIdx.y;
    int b = blockIdx.x;
    const float* Wp; u16* Wsp; int Kd, Nd;
    if (b < 576){ Wp = W1; Wsp = W1s; Kd = DM; Nd = DF; }
    else        { b -= 576; Wp = W2; Wsp = W2s; Kd = DF; Nd = DM; }
    int kbn = Kd >> 5;
    Wp  += (size_t)e*Kd*Nd;
    Wsp += (size_t)e*Kd*Nd;
    int t = threadIdx.x;
    int u = b*256 + t;
    int l   = u & 63;
    int kb  = (u >> 6) % kbn;
    int qq  = (u >> 6) / kbn;
    int ntp = qq & 3;
    int nb  = qq >> 2;
    int k0 = kb*32 + (l >> 4)*8;
    int c  = nb*128 + ntp*32 + (l & 15);
    const float* src = Wp + (size_t)k0*Nd + c;
    short8 o0, o1;
#pragma unroll
    for (int j = 0; j < 8; j++){
        o0[j] = (short)f2b(src[(size_t)j*Nd]);
        o1[j] = (short)f2b(src[(size_t)j*Nd + 16]);
    }
    size_t v0 = ((size_t)(nb*8 + ntp*2)*kbn + kb)*64 + l;
    *(short8*)&Wsp[v0*8] = o0;
    *(short8*)&Wsp[v0*8 + (size_t)kbn*512] = o1;
}

// ---------------- gate (+ x fp32->bf16 fused) ----------------
#define GATE_BLOCKS 128
__global__ __launch_bounds__(256) void gate_kernel(const float* __restrict__ x, const float* __restrict__ Wg,
                                                   int* __restrict__ eid, float* __restrict__ gw,
                                                   int* __restrict__ counts, u16* __restrict__ xb){
    __shared__ int lh[NE];
    int t = threadIdx.x;
    if (t < NE) lh[t] = 0;
    __syncthreads();
    int wv = t >> 6, l = t & 63;
    int wgid = blockIdx.x*4 + wv;
    const int NW = GATE_BLOCKS*4;

    for (int s = wgid; s < S_TOK; s += NW){
        float acc[NE];
#pragma unroll
        for (int e = 0; e < NE; e++) acc[e] = 0.f;
        const float* xr = x + (size_t)s * DM;
        u16* xbr = xb + (size_t)s * DM;
#pragma unroll
        for (int i = 0; i < DM/64; i++){
            int d = l + 64*i;
            float xv = xr[d];
            xbr[d] = f2b(xv);
            float4 w0 = *(const float4*)(Wg + d*NE);
            float4 w1 = *(const float4*)(Wg + d*NE + 4);
            acc[0] += xv*w0.x; acc[1] += xv*w0.y; acc[2] += xv*w0.z; acc[3] += xv*w0.w;
            acc[4] += xv*w1.x; acc[5] += xv*w1.y; acc[6] += xv*w1.z; acc[7] += xv*w1.w;
        }
#pragma unroll
        for (int e = 0; e < NE; e++){
#pragma unroll
            for (int off = 32; off; off >>= 1) acc[e] += __shfl_down(acc[e], off);
        }
        if (l == 0){
            int i1 = 0; float v1 = acc[0];
            for (int e = 1; e < NE; e++) if (acc[e] > v1){ v1 = acc[e]; i1 = e; }
            int i2 = -1; float v2 = -1e30f;
            for (int e = 0; e < NE; e++) if (e != i1 && acc[e] > v2){ v2 = acc[e]; i2 = e; }
            float w0, w1;
            if (i2 < 0){ i2 = (i1 + 1) & 7; w0 = 1.f; w1 = 0.f; }
            else {
                float e2 = expf(v2 - v1);
                w0 = 1.f / (1.f + e2);
                w1 = e2 / (1.f + e2);
            }
            eid[2*s]   = i1; gw[2*s]   = w0;
            eid[2*s+1] = i2; gw[2*s+1] = w1;
            atomicAdd(&lh[i1], 1);
            atomicAdd(&lh[i2], 1);
        }
    }
    __syncthreads();
    if (t < NE && lh[t] > 0) atomicAdd(&counts[t*16], lh[t]);
}

// ---------------- scatter + padfill (offsets computed in-block from counts) ----------------
__global__ __launch_bounds__(256) void scatter_kernel(const int* __restrict__ eid, int* __restrict__ cursor,
                                                      const int* __restrict__ counts,
                                                      int* __restrict__ tok_of, int* __restrict__ pos_of){
    __shared__ int lh[NE];
    __shared__ int base[NE];
    __shared__ int offsP[NE+1];
    int t = threadIdx.x;
    if (t < NE) lh[t] = 0;
    if (t == 0){
        int P = 0;
        for (int q = 0; q < NE; q++){ offsP[q] = P; P += ((counts[q*16] + 127) >> 7) << 7; }
        offsP[NE] = P;
    }
    __syncthreads();
    int i = blockIdx.x*256 + t;
    int e = 0, r = 0;
    if (i < NSLOT){
        e = eid[i];
        if (e < 0) e = 0; if (e > 7) e = 7;
        r = atomicAdd(&lh[e], 1);
    }
    __syncthreads();
    if (t < NE) base[t] = offsP[t] + ((lh[t] > 0) ? atomicAdd(&cursor[t*16], lh[t]) : 0);
    __syncthreads();
    if (i < NSLOT){
        int p = base[e] + r;
        if (p < 0) p = 0; if (p >= PSLOT) p = PSLOT - 1;
        tok_of[p] = i >> 1;
        pos_of[i] = p;
    }
    // padfill: p2 = i in [0, PSLOT)
    int p2 = i;
    int pe = -1;
#pragma unroll
    for (int q = 0; q < NE; q++) if (p2 >= offsP[q] && p2 < offsP[q+1]) pe = q;
    if (pe < 0){ tok_of[p2] = 0; }
    else if (p2 >= offsP[pe] + counts[pe*16]){ tok_of[p2] = 0; }
}

// ---------------- GEMM1: h = relu(x[tok] @ W1[e] + b1[e]) ----------------
// Double-buffered As + Bs, ONE counted-vmcnt barrier per K-step.
__global__ __launch_bounds__(256) void gemm1p_kernel(const u16* __restrict__ xb, const int* __restrict__ tok_of,
                                                     const int* __restrict__ counts, const u16* __restrict__ W1s,
                                                     const float* __restrict__ b1, u16* __restrict__ h){
    const int KB = DM/32;     // 24
    const int NT = DM/64;     // 12
    int bid = blockIdx.x;
    int by = bid % 24, mb = bid / 24;   // XCD = bid%8 = by%8
    int e = expert_of_row(counts, mb*128);
    if (e < 0) return;
    int m0 = mb*128, n0 = by*128;

    int t = threadIdx.x;
    int w = t >> 6, l = t & 63;
    int wm = w & 1, wn = w >> 1;

    __shared__ u16 As[2*128*72];      // 36 KB double-buffered
    __shared__ u16 Bs[2*2*8*512];     // 32 KB double-buffered

    int row0 = t >> 2, kc = t & 3;
    const u16* a0 = xb + (size_t)tok_of[m0 + row0]*DM + kc*8;
    const u16* a1 = xb + (size_t)tok_of[m0 + row0 + 64]*DM + kc*8;
    int aso0 = row0*72 + kc*8;
    int aso1 = (row0 + 64)*72 + kc*8;

    const u16* bbase = W1s + (size_t)e*DM*DF + (size_t)(((n0 >> 4) + 2*w)*KB)*512 + l*8;

#define STB1(kb2, buf) do{ \
    GLDS16(bbase + (size_t)(2*(kb2))*512,                   &Bs[(buf)*8192 + (2*w)*512]); \
    GLDS16(bbase + (size_t)(2*(kb2)+1)*512,                 &Bs[(buf)*8192 + 4096 + (2*w)*512]); \
    GLDS16(bbase + (size_t)KB*512 + (size_t)(2*(kb2))*512,  &Bs[(buf)*8192 + (2*w+1)*512]); \
    GLDS16(bbase + (size_t)KB*512 + (size_t)(2*(kb2)+1)*512,&Bs[(buf)*8192 + 4096 + (2*w+1)*512]); \
}while(0)

    f32x4 acc[4][4];
#pragma unroll
    for (int i = 0; i < 4; i++)
#pragma unroll
        for (int j = 0; j < 4; j++) acc[i][j] = (f32x4){0.f,0.f,0.f,0.f};

    // prologue: A(0)->regs; As^0<-A(0); G(0)->Bs^0; A(1)->regs; wait; barrier
    short8 av0a = *(const short8*)a0;
    short8 av0b = *(const short8*)(a0 + 32);
    short8 av1a = *(const short8*)a1;
    short8 av1b = *(const short8*)(a1 + 32);
    *(short8*)&As[aso0] = av0a; *(short8*)&As[aso0 + 32] = av0b;
    *(short8*)&As[aso1] = av1a; *(short8*)&As[aso1 + 32] = av1b;
    STB1(0, 0);
    av0a = *(const short8*)(a0 + 64);
    av0b = *(const short8*)(a0 + 96);
    av1a = *(const short8*)(a1 + 64);
    av1b = *(const short8*)(a1 + 96);
    // in-flight: G(0)[4 oldest], A(1)[4] -> vmcnt(4) retires G(0)
    __builtin_amdgcn_sched_barrier(0);
    asm volatile("s_waitcnt vmcnt(4) lgkmcnt(0)" ::: "memory");
    __builtin_amdgcn_sched_barrier(0);
    __builtin_amdgcn_s_barrier();

    for (int kt = 0; kt < NT; kt++){
        int p = kt & 1, q = p ^ 1;
        if (kt + 1 < NT){
            // As^q <- A(kt+1) regs (auto-wait on av); issue B(kt+1)->Bs^q; A(kt+2)->regs
            *(short8*)&As[q*9216 + aso0] = av0a; *(short8*)&As[q*9216 + aso0 + 32] = av0b;
            *(short8*)&As[q*9216 + aso1] = av1a; *(short8*)&As[q*9216 + aso1 + 32] = av1b;
            STB1(kt + 1, q);
            if (kt + 2 < NT){
                av0a = *(const short8*)(a0 + (kt+2)*64);
                av0b = *(const short8*)(a0 + (kt+2)*64 + 32);
                av1a = *(const short8*)(a1 + (kt+2)*64);
                av1b = *(const short8*)(a1 + (kt+2)*64 + 32);
            }
        }
#pragma unroll
        for (int ks = 0; ks < 2; ks++){
            short8 af[4], bf[4];
#pragma unroll
            for (int mt = 0; mt < 4; mt++)
                af[mt] = *(const short8*)&As[p*9216 + (wm*64 + mt*16 + (l & 15))*72 + ks*32 + (l >> 4)*8];
#pragma unroll
            for (int nt = 0; nt < 4; nt++)
                bf[nt] = *(const short8*)&Bs[p*8192 + ks*4096 + (wn*4 + nt)*512 + l*8];
#pragma unroll
            for (int mt = 0; mt < 4; mt++)
#pragma unroll
                for (int nt = 0; nt < 4; nt++)
                    acc[mt][nt] = __builtin_amdgcn_mfma_f32_16x16x32_bf16(af[mt], bf[nt], acc[mt][nt], 0, 0, 0);
        }
        // end-of-step: in-flight {G(kt+1)[4 oldest], A(kt+2)[4]} -> vmcnt(4); tail drains
        __builtin_amdgcn_sched_barrier(0);
        if (kt + 2 < NT){
            asm volatile("s_waitcnt vmcnt(4) lgkmcnt(0)" ::: "memory");
        } else {
            asm volatile("s_waitcnt vmcnt(0) lgkmcnt(0)" ::: "memory");
        }
        __builtin_amdgcn_sched_barrier(0);
        __builtin_amdgcn_s_barrier();
    }
#undef STB1

#pragma unroll
    for (int nt = 0; nt < 4; nt++){
        int col = n0 + wn*64 + nt*16 + (l & 15);
        float bv = b1[e*DF + col];
#pragma unroll
        for (int mt = 0; mt < 4; mt++){
#pragma unroll
            for (int r = 0; r < 4; r++){
                int grow = m0 + wm*64 + mt*16 + (l >> 4)*4 + r;
                float v = acc[mt][nt][r] + bv;
                v = v > 0.f ? v : 0.f;
                h[(size_t)grow*DF + col] = f2b(v);
            }
        }
    }
}

// ---------------- GEMM2: y[slot] = h[slot] @ W2[e] + b2[e] ----------------
// Double-buffered As + Bs, ONE counted-vmcnt barrier per K-step.
__global__ __launch_bounds__(256) void gemm2p_kernel(const u16* __restrict__ h, const int* __restrict__ counts,
                                                     const u16* __restrict__ W2s, const float* __restrict__ b2,
                                                     float* __restrict__ y){
    const int KB = DF/32;     // 96
    const int NT = DF/64;     // 48
    int bid = blockIdx.x;
    int mb = bid % MBMAX;     // XCD = bid%8 = mb%8
    int by = bid / MBMAX;     // 0..5
    int e = expert_of_row(counts, mb*128);
    if (e < 0) return;
    int m0 = mb*128, n0 = by*128;

    int t = threadIdx.x;
    int w = t >> 6, l = t & 63;
    int wm = w & 1, wn = w >> 1;

    __shared__ u16 As[2*128*72];      // 36 KB
    __shared__ u16 Bs[2*2*8*512];     // 32 KB

    int row0 = t >> 2, kc = t & 3;
    const u16* a0 = h + (size_t)(m0 + row0)*DF + kc*8;
    const u16* a1 = h + (size_t)(m0 + row0 + 64)*DF + kc*8;
    int aso0 = row0*72 + kc*8;
    int aso1 = (row0 + 64)*72 + kc*8;

    const u16* bbase = W2s + (size_t)e*DF*DM + (size_t)(((n0 >> 4) + 2*w)*KB)*512 + l*8;

#define STB2(kb2, buf) do{ \
    GLDS16(bbase + (size_t)(2*(kb2))*512,                   &Bs[(buf)*8192 + (2*w)*512]); \
    GLDS16(bbase + (size_t)(2*(kb2)+1)*512,                 &Bs[(buf)*8192 + 4096 + (2*w)*512]); \
    GLDS16(bbase + (size_t)KB*512 + (size_t)(2*(kb2))*512,  &Bs[(buf)*8192 + (2*w+1)*512]); \
    GLDS16(bbase + (size_t)KB*512 + (size_t)(2*(kb2)+1)*512,&Bs[(buf)*8192 + 4096 + (2*w+1)*512]); \
}while(0)

    f32x4 acc[4][4];
#pragma unroll
    for (int i = 0; i < 4; i++)
#pragma unroll
        for (int j = 0; j < 4; j++) acc[i][j] = (f32x4){0.f,0.f,0.f,0.f};

    short8 av0a = *(const short8*)a0;
    short8 av0b = *(const short8*)(a0 + 32);
    short8 av1a = *(const short8*)a1;
    short8 av1b = *(const short8*)(a1 + 32);
    *(short8*)&As[aso0] = av0a; *(short8*)&As[aso0 + 32] = av0b;
    *(short8*)&As[aso1] = av1a; *(short8*)&As[aso1 + 32] = av1b;
    STB2(0, 0);
    av0a = *(const short8*)(a0 + 64);
    av0b = *(const short8*)(a0 + 96);
    av1a = *(const short8*)(a1 + 64);
    av1b = *(const short8*)(a1 + 96);
    __builtin_amdgcn_sched_barrier(0);
    asm volatile("s_waitcnt vmcnt(4) lgkmcnt(0)" ::: "memory");
    __builtin_amdgcn_sched_barrier(0);
    __builtin_amdgcn_s_barrier();

    for (int kt = 0; kt < NT; kt++){
        int p = kt & 1, q = p ^ 1;
        if (kt + 1 < NT){
            *(short8*)&As[q*9216 + aso0] = av0a; *(short8*)&As[q*9216 + aso0 + 32] = av0b;
            *(short8*)&As[q*9216 + aso1] = av1a; *(short8*)&As[q*9216 + aso1 + 32] = av1b;
            STB2(kt + 1, q);
            if (kt + 2 < NT){
                av0a = *(const short8*)(a0 + (kt+2)*64);
                av0b = *(const short8*)(a0 + (kt+2)*64 + 32);
                av1a = *(const short8*)(a1 + (kt+2)*64);
                av1b = *(const short8*)(a1 + (kt+2)*64 + 32);
            }
        }
#pragma unroll
        for (int ks = 0; ks < 2; ks++){
            short8 af[4], bf[4];
#pragma unroll
            for (int mt = 0; mt < 4; mt++)
                af[mt] = *(const short8*)&As[p*9216 + (wm*64 + mt*16 + (l & 15))*72 + ks*32 + (l >> 4)*8];
#pragma unroll
            for (int nt = 0; nt < 4; nt++)
                bf[nt] = *(const short8*)&Bs[p*8192 + ks*4096 + (wn*4 + nt)*512 + l*8];
#pragma unroll
            for (int mt = 0; mt < 4; mt++)
#pragma unroll
                for (int nt = 0; nt < 4; nt++)
                    acc[mt][nt] = __builtin_amdgcn_mfma_f32_16x16x32_bf16(af[mt], bf[nt], acc[mt][nt], 0, 0, 0);
        }
        __builtin_amdgcn_sched_barrier(0);
        if (kt + 2 < NT){
            asm volatile("s_waitcnt vmcnt(4) lgkmcnt(0)" ::: "memory");
        } else {
            asm volatile("s_waitcnt vmcnt(0) lgkmcnt(0)" ::: "memory");
        }
        __builtin_amdgcn_sched_barrier(0);
        __builtin_amdgcn_s_barrier();
    }
#undef STB2

#pragma unroll
    for (int nt = 0; nt < 4; nt++){
        int col = n0 + wn*64 + nt*16 + (l & 15);
        float bv = b2[e*DM + col];
#pragma unroll
        for (int mt = 0; mt < 4; mt++){
#pragma unroll
            for (int r = 0; r < 4; r++){
                int grow = m0 + wm*64 + mt*16 + (l >> 4)*4 + r;
                y[(size_t)grow*DM + col] = acc[mt][nt][r] + bv;
            }
        }
    }
}

// ---------------- combine: out[s] = w0*y[pos(s,0)] + w1*y[pos(s,1)] ----------------
__global__ __launch_bounds__(256) void combine_kernel(const float* __restrict__ y, const int* __restrict__ pos_of,
                                                      const float* __restrict__ gw, float* __restrict__ out){
    int i = blockIdx.x*256 + threadIdx.x;   // float4 index
    int s = i / (DM/4);
    int c4 = (i - s*(DM/4))*4;
    int p0 = pos_of[2*s], p1 = pos_of[2*s+1];
    float w0 = gw[2*s], w1 = gw[2*s+1];
    float4 a = *(const float4*)&y[(size_t)p0*DM + c4];
    float4 b = *(const float4*)&y[(size_t)p1*DM + c4];
    float4 o;
    o.x = w0*a.x + w1*b.x;
    o.y = w0*a.y + w1*b.y;
    o.z = w0*a.z + w1*b.z;
    o.w = w0*a.w + w1*b.w;
    *(float4*)&out[(size_t)s*DM + c4] = o;
}

// ---------------- zero-workspace fallback ----------------
__global__ __launch_bounds__(256) void fallback_kernel(const float* __restrict__ x, const float* __restrict__ Wg,
                                                       const float* __restrict__ W1, const float* __restrict__ b1,
                                                       const float* __restrict__ W2, const float* __restrict__ b2,
                                                       float* __restrict__ out){
    int s = blockIdx.x;
    int t = threadIdx.x;
    __shared__ float xr[DM];
    __shared__ float hl[DF];
    __shared__ float yl[DM];
    __shared__ float lacc[4*NE];
    __shared__ int   sel_e[2];
    __shared__ float sel_w[2];

    for (int i = t; i < DM; i += 256){ xr[i] = x[(size_t)s*DM + i]; yl[i] = 0.f; }
    __syncthreads();

    float acc[NE];
#pragma unroll
    for (int e = 0; e < NE; e++) acc[e] = 0.f;
    for (int d = t*3; d < t*3 + 3; d++){
        float xv = xr[d];
#pragma unroll
        for (int e = 0; e < NE; e++) acc[e] += xv * Wg[d*NE + e];
    }
#pragma unroll
    for (int e = 0; e < NE; e++){
#pragma unroll
        for (int off = 32; off; off >>= 1) acc[e] += __shfl_down(acc[e], off);
    }
    if ((t & 63) == 0){
        int wv = t >> 6;
#pragma unroll
        for (int e = 0; e < NE; e++) lacc[wv*NE + e] = acc[e];
    }
    __syncthreads();
    if (t == 0){
        float lg[NE];
#pragma unroll
        for (int e = 0; e < NE; e++) lg[e] = lacc[e] + lacc[NE + e] + lacc[2*NE + e] + lacc[3*NE + e];
        int i1 = 0; float v1 = lg[0];
        for (int e = 1; e < NE; e++) if (lg[e] > v1){ v1 = lg[e]; i1 = e; }
        int i2 = -1; float v2 = -1e30f;
        for (int e = 0; e < NE; e++) if (e != i1 && lg[e] > v2){ v2 = lg[e]; i2 = e; }
        if (i2 < 0){ i2 = (i1 + 1) & 7; sel_w[0] = 1.f; sel_w[1] = 0.f; }
        else {
            float e2 = expf(v2 - v1);
            sel_w[0] = 1.f / (1.f + e2);
            sel_w[1] = e2 / (1.f + e2);
        }
        sel_e[0] = i1; sel_e[1] = i2;
    }
    __syncthreads();

    for (int kk = 0; kk < 2; kk++){
        int e = sel_e[kk];
        float wgt = sel_w[kk];
        const float* w1p = W1 + (size_t)e * DM * DF;
        for (int j = t; j < DF; j += 256){
            float a = b1[e*DF + j];
            for (int k = 0; k < DM; k++) a += xr[k] * w1p[(size_t)k*DF + j];
            hl[j] = a > 0.f ? a : 0.f;
        }
        __syncthreads();
        const float* w2p = W2 + (size_t)e * DF * DM;
        for (int c = t; c < DM; c += 256){
            float a = b2[e*DM + c];
            for (int k = 0; k < DF; k++) a += hl[k] * w2p[(size_t)k*DM + c];
            yl[c] += wgt * a;
        }
        __syncthreads();
    }
    for (int c = t; c < DM; c += 256) out[(size_t)s*DM + c] = yl[c];
}

extern "C" void kernel_launch(void* const* d_in, const int* in_sizes, int n_in,
                              void* d_out, int out_size, void* d_ws, size_t ws_size,
                              hipStream_t stream) {
    const float* x  = (const float*)d_in[0];
    const float* Wg = (const float*)d_in[1];
    const float* W1 = (const float*)d_in[2];
    const float* b1 = (const float*)d_in[3];
    const float* W2 = (const float*)d_in[4];
    const float* b2 = (const float*)d_in[5];
    float* out = (float*)d_out;

    char* ws = (char*)d_ws;
    int*   counts = (int*)(ws + WS_COUNTS);
    int*   cursor = (int*)(ws + WS_CURSOR);
    int*   eid    = (int*)(ws + WS_EID);
    float* gw     = (float*)(ws + WS_GW);
    int*   pos_of = (int*)(ws + WS_POS);
    int*   tok_of = (int*)(ws + WS_TOK);

    const size_t xbB = (size_t)S_TOK*DM*2;           //  6.29 MB
    const size_t wB  = (size_t)NE*DM*DF*2;           // 37.75 MB each
    const size_t hB  = (size_t)PSLOT*DF*2;           // 56.62 MB
    const size_t need = CTRL_BYTES + xbB + 2*wB + hB;  // 138.7 MB

    if (ws_size < need){
        fallback_kernel<<<S_TOK, 256, 0, stream>>>(x, Wg, W1, b1, W2, b2, out);
        return;
    }

    u16* xb  = (u16*)(ws + CTRL_BYTES);
    u16* W1s = (u16*)(ws + CTRL_BYTES + xbB);
    u16* W2s = (u16*)(ws + CTRL_BYTES + xbB + wB);
    u16* h   = (u16*)(ws + CTRL_BYTES + xbB + 2*wB);
    // y (28.3 MB fp32) reuses the W1s region (37.75 MB) — W1s is dead once gemm1 completes.
    float* yb = (float*)(ws + CTRL_BYTES + xbB);

    cvtw_kernel<<<dim3(1152, NE), 256, 0, stream>>>(W1, W1s, W2, W2s, counts, cursor);
    gate_kernel<<<GATE_BLOCKS, 256, 0, stream>>>(x, Wg, eid, gw, counts, xb);
    scatter_kernel<<<PSLOT/256, 256, 0, stream>>>(eid, cursor, counts, tok_of, pos_of);

    gemm1p_kernel<<<MBMAX*24, 256, 0, stream>>>(xb, tok_of, counts, W1s, b1, h);
    gemm2p_kernel<<<6*MBMAX, 256, 0, stream>>>(h, counts, W2s, b2, yb);
    combine_kernel<<<(S_TOK*(DM/4))/256, 256, 0, stream>>>(yb, pos_of, gw, out);
}

// Round 10
// 329.908 us; speedup vs baseline: 1.0773x; 1.0773x over previous
//
#include <hip/hip_runtime.h>
#include <math.h>

typedef short short8 __attribute__((ext_vector_type(8)));
typedef float f32x4 __attribute__((ext_vector_type(4)));
typedef unsigned short u16;
typedef unsigned int u32;

#define S_TOK 4096
#define DM 768
#define DF 3072
#define NE 8
#define NSLOT (S_TOK*2)      // 8192 real slots
#define PSLOT 9216           // padded capacity (8192 + 8*127 rounded up)
#define MBMAX 72             // PSLOT/128
#define TMAX  33             // max 128-row tiles per expert (count<=4096 -> padded<=4224)

// ---- control block ----
#define WS_COUNTS   0        // 128 ints (8 x 16-int stride)
#define WS_CURSOR   512      // 128 ints (zero-based rank cursor)
#define WS_EID      2048     // NSLOT ints
#define WS_GW       (WS_EID + NSLOT*4)
#define WS_POS      (WS_GW  + NSLOT*4)      // NSLOT ints
#define WS_TOK      (WS_POS + NSLOT*4)      // PSLOT ints
#define CTRL_BYTES  262144

#define AS1 __attribute__((address_space(1)))
#define AS3 __attribute__((address_space(3)))
#define GLDS16(g, s) __builtin_amdgcn_global_load_lds((const AS1 u32*)(g), (AS3 u32*)(s), 16, 0, 0)

__device__ inline u16 f2b(float f){
    u32 u = __builtin_bit_cast(u32, f);
    u32 r = (u + 0x7fffu + ((u >> 16) & 1u)) >> 16;   // RNE
    return (u16)r;
}

// ---------------- W fp32 [e][K][N] -> bf16 fragment order, direct gather ----------------
__global__ __launch_bounds__(256) void cvtw_kernel(const float* __restrict__ W1, u16* __restrict__ W1s,
                                                   const float* __restrict__ W2, u16* __restrict__ W2s,
                                                   int* __restrict__ counts, int* __restrict__ cursor){
    if (blockIdx.x == 0 && blockIdx.y == 0 && threadIdx.x < 128){
        counts[threadIdx.x] = 0; cursor[threadIdx.x] = 0;
    }
    int e = blockIdx.y;
    int b = blockIdx.x;
    const float* Wp; u16* Wsp; int Kd, Nd;
    if (b < 576){ Wp = W1; Wsp = W1s; Kd = DM; Nd = DF; }
    else        { b -= 576; Wp = W2; Wsp = W2s; Kd = DF; Nd = DM; }
    int kbn = Kd >> 5;
    Wp  += (size_t)e*Kd*Nd;
    Wsp += (size_t)e*Kd*Nd;
    int t = threadIdx.x;
    int u = b*256 + t;
    int l   = u & 63;
    int kb  = (u >> 6) % kbn;
    int qq  = (u >> 6) / kbn;
    int ntp = qq & 3;
    int nb  = qq >> 2;
    int k0 = kb*32 + (l >> 4)*8;
    int c  = nb*128 + ntp*32 + (l & 15);
    const float* src = Wp + (size_t)k0*Nd + c;
    short8 o0, o1;
#pragma unroll
    for (int j = 0; j < 8; j++){
        o0[j] = (short)f2b(src[(size_t)j*Nd]);
        o1[j] = (short)f2b(src[(size_t)j*Nd + 16]);
    }
    size_t v0 = ((size_t)(nb*8 + ntp*2)*kbn + kb)*64 + l;
    *(short8*)&Wsp[v0*8] = o0;
    *(short8*)&Wsp[v0*8 + (size_t)kbn*512] = o1;
}

// ---------------- gate (+ x fp32->bf16 fused) ----------------
#define GATE_BLOCKS 128
__global__ __launch_bounds__(256) void gate_kernel(const float* __restrict__ x, const float* __restrict__ Wg,
                                                   int* __restrict__ eid, float* __restrict__ gw,
                                                   int* __restrict__ counts, u16* __restrict__ xb){
    __shared__ int lh[NE];
    int t = threadIdx.x;
    if (t < NE) lh[t] = 0;
    __syncthreads();
    int wv = t >> 6, l = t & 63;
    int wgid = blockIdx.x*4 + wv;
    const int NW = GATE_BLOCKS*4;

    for (int s = wgid; s < S_TOK; s += NW){
        float acc[NE];
#pragma unroll
        for (int e = 0; e < NE; e++) acc[e] = 0.f;
        const float* xr = x + (size_t)s * DM;
        u16* xbr = xb + (size_t)s * DM;
#pragma unroll
        for (int i = 0; i < DM/64; i++){
            int d = l + 64*i;
            float xv = xr[d];
            xbr[d] = f2b(xv);
            float4 w0 = *(const float4*)(Wg + d*NE);
            float4 w1 = *(const float4*)(Wg + d*NE + 4);
            acc[0] += xv*w0.x; acc[1] += xv*w0.y; acc[2] += xv*w0.z; acc[3] += xv*w0.w;
            acc[4] += xv*w1.x; acc[5] += xv*w1.y; acc[6] += xv*w1.z; acc[7] += xv*w1.w;
        }
#pragma unroll
        for (int e = 0; e < NE; e++){
#pragma unroll
            for (int off = 32; off; off >>= 1) acc[e] += __shfl_down(acc[e], off);
        }
        if (l == 0){
            int i1 = 0; float v1 = acc[0];
            for (int e = 1; e < NE; e++) if (acc[e] > v1){ v1 = acc[e]; i1 = e; }
            int i2 = -1; float v2 = -1e30f;
            for (int e = 0; e < NE; e++) if (e != i1 && acc[e] > v2){ v2 = acc[e]; i2 = e; }
            float w0, w1;
            if (i2 < 0){ i2 = (i1 + 1) & 7; w0 = 1.f; w1 = 0.f; }
            else {
                float e2 = expf(v2 - v1);
                w0 = 1.f / (1.f + e2);
                w1 = e2 / (1.f + e2);
            }
            eid[2*s]   = i1; gw[2*s]   = w0;
            eid[2*s+1] = i2; gw[2*s+1] = w1;
            atomicAdd(&lh[i1], 1);
            atomicAdd(&lh[i2], 1);
        }
    }
    __syncthreads();
    if (t < NE && lh[t] > 0) atomicAdd(&counts[t*16], lh[t]);
}

// ---------------- scatter + padfill (offsets computed in-block from counts) ----------------
__global__ __launch_bounds__(256) void scatter_kernel(const int* __restrict__ eid, int* __restrict__ cursor,
                                                      const int* __restrict__ counts,
                                                      int* __restrict__ tok_of, int* __restrict__ pos_of){
    __shared__ int lh[NE];
    __shared__ int base[NE];
    __shared__ int offsP[NE+1];
    int t = threadIdx.x;
    if (t < NE) lh[t] = 0;
    if (t == 0){
        int P = 0;
        for (int q = 0; q < NE; q++){ offsP[q] = P; P += ((counts[q*16] + 127) >> 7) << 7; }
        offsP[NE] = P;
    }
    __syncthreads();
    int i = blockIdx.x*256 + t;
    int e = 0, r = 0;
    if (i < NSLOT){
        e = eid[i];
        if (e < 0) e = 0; if (e > 7) e = 7;
        r = atomicAdd(&lh[e], 1);
    }
    __syncthreads();
    if (t < NE) base[t] = offsP[t] + ((lh[t] > 0) ? atomicAdd(&cursor[t*16], lh[t]) : 0);
    __syncthreads();
    if (i < NSLOT){
        int p = base[e] + r;
        if (p < 0) p = 0; if (p >= PSLOT) p = PSLOT - 1;
        tok_of[p] = i >> 1;
        pos_of[i] = p;
    }
    int p2 = i;
    int pe = -1;
#pragma unroll
    for (int q = 0; q < NE; q++) if (p2 >= offsP[q] && p2 < offsP[q+1]) pe = q;
    if (pe < 0){ tok_of[p2] = 0; }
    else if (p2 >= offsP[pe] + counts[pe*16]){ tok_of[p2] = 0; }
}

// expert-partition decode: bid = (strip*TMAX + ti)*8 + e  ->  XCD(bid%8) == e
// returns m0 row or -1 (dead tile)
__device__ inline int decode_tile(const int* __restrict__ counts, int bid, int* e_out, int* strip_out){
    int e  = bid & 7;
    int r  = bid >> 3;
    int ti = r % TMAX;
    int strip = r / TMAX;
    int offs_e = 0, padded_e = 0;
#pragma unroll
    for (int q = 0; q < NE; q++){
        int pq = ((counts[q*16] + 127) >> 7) << 7;
        if (q < e) offs_e += pq;
        if (q == e) padded_e = pq;
    }
    *e_out = e; *strip_out = strip;
    if (ti*128 >= padded_e) return -1;
    return offs_e + ti*128;
}

// ---------------- GEMM1: h = relu(x[tok] @ W1[e] + b1[e]) ----------------
// 2-buffer counted-vmcnt pipeline (r8, passing); expert->XCD block mapping.
__global__ __launch_bounds__(256) void gemm1p_kernel(const u16* __restrict__ xb, const int* __restrict__ tok_of,
                                                     const int* __restrict__ counts, const u16* __restrict__ W1s,
                                                     const float* __restrict__ b1, u16* __restrict__ h){
    const int KB = DM/32;     // 24
    const int NT = DM/64;     // 12
    int e, by;
    int m0 = decode_tile(counts, blockIdx.x, &e, &by);   // by = 0..23
    if (m0 < 0) return;
    int n0 = by*128;

    int t = threadIdx.x;
    int w = t >> 6, l = t & 63;
    int wm = w & 1, wn = w >> 1;

    __shared__ u16 As[128*72];        // 18 KB
    __shared__ u16 Bs[2*2*8*512];     // 32 KB

    int row0 = t >> 2, kc = t & 3;
    const u16* a0 = xb + (size_t)tok_of[m0 + row0]*DM + kc*8;
    const u16* a1 = xb + (size_t)tok_of[m0 + row0 + 64]*DM + kc*8;
    u16* as0 = &As[row0*72 + kc*8];
    u16* as1 = &As[(row0 + 64)*72 + kc*8];

    const u16* bbase = W1s + (size_t)e*DM*DF + (size_t)(((n0 >> 4) + 2*w)*KB)*512 + l*8;

#define STB1(kb2, buf) do{ \
    GLDS16(bbase + (size_t)(2*(kb2))*512,                   &Bs[(buf)*8192 + (2*w)*512]); \
    GLDS16(bbase + (size_t)(2*(kb2)+1)*512,                 &Bs[(buf)*8192 + 4096 + (2*w)*512]); \
    GLDS16(bbase + (size_t)KB*512 + (size_t)(2*(kb2))*512,  &Bs[(buf)*8192 + (2*w+1)*512]); \
    GLDS16(bbase + (size_t)KB*512 + (size_t)(2*(kb2)+1)*512,&Bs[(buf)*8192 + 4096 + (2*w+1)*512]); \
}while(0)

    f32x4 acc[4][4];
#pragma unroll
    for (int i = 0; i < 4; i++)
#pragma unroll
        for (int j = 0; j < 4; j++) acc[i][j] = (f32x4){0.f,0.f,0.f,0.f};

    short8 av0a = *(const short8*)a0;
    short8 av0b = *(const short8*)(a0 + 32);
    short8 av1a = *(const short8*)a1;
    short8 av1b = *(const short8*)(a1 + 32);
    STB1(0, 0);
    *(short8*)as0 = av0a; *(short8*)(as0 + 32) = av0b;
    *(short8*)as1 = av1a; *(short8*)(as1 + 32) = av1b;
    av0a = *(const short8*)(a0 + 64);
    av0b = *(const short8*)(a0 + 96);
    av1a = *(const short8*)(a1 + 64);
    av1b = *(const short8*)(a1 + 96);
    // outstanding: G0(4, oldest), A1(4, newest) -> vmcnt(4): G0 landed
    __builtin_amdgcn_sched_barrier(0);
    asm volatile("s_waitcnt vmcnt(4) lgkmcnt(0)" ::: "memory");
    __builtin_amdgcn_sched_barrier(0);
    __builtin_amdgcn_s_barrier();

    int cb = 0;
    for (int kt = 0; kt < NT; kt++){
        if (kt + 1 < NT) STB1(kt + 1, cb ^ 1);
#pragma unroll
        for (int ks = 0; ks < 2; ks++){
            short8 af[4], bf[4];
#pragma unroll
            for (int mt = 0; mt < 4; mt++)
                af[mt] = *(const short8*)&As[(wm*64 + mt*16 + (l & 15))*72 + ks*32 + (l >> 4)*8];
#pragma unroll
            for (int nt = 0; nt < 4; nt++)
                bf[nt] = *(const short8*)&Bs[cb*8192 + ks*4096 + (wn*4 + nt)*512 + l*8];
#pragma unroll
            for (int mt = 0; mt < 4; mt++)
#pragma unroll
                for (int nt = 0; nt < 4; nt++)
                    acc[mt][nt] = __builtin_amdgcn_mfma_f32_16x16x32_bf16(af[mt], bf[nt], acc[mt][nt], 0, 0, 0);
        }
        // outstanding: A(kt+1)[4 oldest], G(kt+1)[4 newest] -> vmcnt(4): A(kt+1) retired.
        __builtin_amdgcn_sched_barrier(0);
        asm volatile("s_waitcnt vmcnt(4) lgkmcnt(0)" ::: "memory");
        __builtin_amdgcn_sched_barrier(0);
        __builtin_amdgcn_s_barrier();
        if (kt + 1 < NT){
            *(short8*)as0 = av0a; *(short8*)(as0 + 32) = av0b;
            *(short8*)as1 = av1a; *(short8*)(as1 + 32) = av1b;
            if (kt + 2 < NT){
                av0a = *(const short8*)(a0 + (kt+2)*64);
                av0b = *(const short8*)(a0 + (kt+2)*64 + 32);
                av1a = *(const short8*)(a1 + (kt+2)*64);
                av1b = *(const short8*)(a1 + (kt+2)*64 + 32);
                __builtin_amdgcn_sched_barrier(0);
                asm volatile("s_waitcnt vmcnt(4) lgkmcnt(0)" ::: "memory");
                __builtin_amdgcn_sched_barrier(0);
            } else {
                __builtin_amdgcn_sched_barrier(0);
                asm volatile("s_waitcnt vmcnt(0) lgkmcnt(0)" ::: "memory");
                __builtin_amdgcn_sched_barrier(0);
            }
            __builtin_amdgcn_s_barrier();
        }
        cb ^= 1;
    }
#undef STB1

#pragma unroll
    for (int nt = 0; nt < 4; nt++){
        int col = n0 + wn*64 + nt*16 + (l & 15);
        float bv = b1[e*DF + col];
#pragma unroll
        for (int mt = 0; mt < 4; mt++){
#pragma unroll
            for (int r = 0; r < 4; r++){
                int grow = m0 + wm*64 + mt*16 + (l >> 4)*4 + r;
                float v = acc[mt][nt][r] + bv;
                v = v > 0.f ? v : 0.f;
                h[(size_t)grow*DF + col] = f2b(v);
            }
        }
    }
}

// ---------------- GEMM2: y[slot] = h[slot] @ W2[e] + b2[e] ----------------
// 3-buffer counted-vmcnt pipeline (r7 champion); expert->XCD block mapping.
__global__ __launch_bounds__(256) void gemm2p_kernel(const u16* __restrict__ h, const int* __restrict__ counts,
                                                     const u16* __restrict__ W2s, const float* __restrict__ b2,
                                                     float* __restrict__ y){
    const int KB = DF/32;     // 96
    const int NT = DF/64;     // 48
    int e, by;
    int m0 = decode_tile(counts, blockIdx.x, &e, &by);   // by = 0..5
    if (m0 < 0) return;
    int n0 = by*128;

    int t = threadIdx.x;
    int w = t >> 6, l = t & 63;
    int wm = w & 1, wn = w >> 1;

    __shared__ u16 As[128*72];        // 18 KB
    __shared__ u16 Bs[3*2*8*512];     // 48 KB

    int row0 = t >> 2, kc = t & 3;
    const u16* a0 = h + (size_t)(m0 + row0)*DF + kc*8;
    const u16* a1 = h + (size_t)(m0 + row0 + 64)*DF + kc*8;
    u16* as0 = &As[row0*72 + kc*8];
    u16* as1 = &As[(row0 + 64)*72 + kc*8];

    const u16* bbase = W2s + (size_t)e*DF*DM + (size_t)(((n0 >> 4) + 2*w)*KB)*512 + l*8;

#define STB2(kb2, buf) do{ \
    GLDS16(bbase + (size_t)(2*(kb2))*512,                   &Bs[(buf)*8192 + (2*w)*512]); \
    GLDS16(bbase + (size_t)(2*(kb2)+1)*512,                 &Bs[(buf)*8192 + 4096 + (2*w)*512]); \
    GLDS16(bbase + (size_t)KB*512 + (size_t)(2*(kb2))*512,  &Bs[(buf)*8192 + (2*w+1)*512]); \
    GLDS16(bbase + (size_t)KB*512 + (size_t)(2*(kb2)+1)*512,&Bs[(buf)*8192 + 4096 + (2*w+1)*512]); \
}while(0)

    f32x4 acc[4][4];
#pragma unroll
    for (int i = 0; i < 4; i++)
#pragma unroll
        for (int j = 0; j < 4; j++) acc[i][j] = (f32x4){0.f,0.f,0.f,0.f};

    short8 av0a = *(const short8*)a0;
    short8 av0b = *(const short8*)(a0 + 32);
    short8 av1a = *(const short8*)a1;
    short8 av1b = *(const short8*)(a1 + 32);
    STB2(0, 0);
    STB2(1, 1);
    *(short8*)as0 = av0a; *(short8*)(as0 + 32) = av0b;
    *(short8*)as1 = av1a; *(short8*)(as1 + 32) = av1b;
    av0a = *(const short8*)(a0 + 64);
    av0b = *(const short8*)(a0 + 96);
    av1a = *(const short8*)(a1 + 64);
    av1b = *(const short8*)(a1 + 96);
    // outstanding: G0(4,oldest), G1(4), A1(4,newest) -> vmcnt(8): G0 landed
    __builtin_amdgcn_sched_barrier(0);
    asm volatile("s_waitcnt vmcnt(8) lgkmcnt(0)" ::: "memory");
    __builtin_amdgcn_sched_barrier(0);
    __builtin_amdgcn_s_barrier();

    int cb = 0, sb = 2;
    for (int kt = 0; kt < NT; kt++){
        if (kt + 2 < NT) STB2(kt + 2, sb);
#pragma unroll
        for (int ks = 0; ks < 2; ks++){
            short8 af[4], bf[4];
#pragma unroll
            for (int mt = 0; mt < 4; mt++)
                af[mt] = *(const short8*)&As[(wm*64 + mt*16 + (l & 15))*72 + ks*32 + (l >> 4)*8];
#pragma unroll
            for (int nt = 0; nt < 4; nt++)
                bf[nt] = *(const short8*)&Bs[cb*8192 + ks*4096 + (wn*4 + nt)*512 + l*8];
#pragma unroll
            for (int mt = 0; mt < 4; mt++)
#pragma unroll
                for (int nt = 0; nt < 4; nt++)
                    acc[mt][nt] = __builtin_amdgcn_mfma_f32_16x16x32_bf16(af[mt], bf[nt], acc[mt][nt], 0, 0, 0);
        }
        // in-flight: G(t+1) oldest, A(t+1), G(t+2) newest -> vmcnt(4): G(t+1)+A(t+1) done.
        __builtin_amdgcn_sched_barrier(0);
        asm volatile("s_waitcnt vmcnt(4) lgkmcnt(0)" ::: "memory");
        __builtin_amdgcn_sched_barrier(0);
        __builtin_amdgcn_s_barrier();
        if (kt + 1 < NT){
            *(short8*)as0 = av0a; *(short8*)(as0 + 32) = av0b;
            *(short8*)as1 = av1a; *(short8*)(as1 + 32) = av1b;
            if (kt + 2 < NT){
                av0a = *(const short8*)(a0 + (kt+2)*64);
                av0b = *(const short8*)(a0 + (kt+2)*64 + 32);
                av1a = *(const short8*)(a1 + (kt+2)*64);
                av1b = *(const short8*)(a1 + (kt+2)*64 + 32);
            }
            __builtin_amdgcn_sched_barrier(0);
            asm volatile("s_waitcnt lgkmcnt(0)" ::: "memory");
            __builtin_amdgcn_sched_barrier(0);
            __builtin_amdgcn_s_barrier();
        }
        cb = (cb == 2) ? 0 : cb + 1;
        sb = (sb == 2) ? 0 : sb + 1;
    }
#undef STB2

#pragma unroll
    for (int nt = 0; nt < 4; nt++){
        int col = n0 + wn*64 + nt*16 + (l & 15);
        float bv = b2[e*DM + col];
#pragma unroll
        for (int mt = 0; mt < 4; mt++){
#pragma unroll
            for (int r = 0; r < 4; r++){
                int grow = m0 + wm*64 + mt*16 + (l >> 4)*4 + r;
                y[(size_t)grow*DM + col] = acc[mt][nt][r] + bv;
            }
        }
    }
}

// ---------------- combine: out[s] = w0*y[pos(s,0)] + w1*y[pos(s,1)] ----------------
__global__ __launch_bounds__(256) void combine_kernel(const float* __restrict__ y, const int* __restrict__ pos_of,
                                                      const float* __restrict__ gw, float* __restrict__ out){
    int i = blockIdx.x*256 + threadIdx.x;
    int s = i / (DM/4);
    int c4 = (i - s*(DM/4))*4;
    int p0 = pos_of[2*s], p1 = pos_of[2*s+1];
    float w0 = gw[2*s], w1 = gw[2*s+1];
    float4 a = *(const float4*)&y[(size_t)p0*DM + c4];
    float4 b = *(const float4*)&y[(size_t)p1*DM + c4];
    float4 o;
    o.x = w0*a.x + w1*b.x;
    o.y = w0*a.y + w1*b.y;
    o.z = w0*a.z + w1*b.z;
    o.w = w0*a.w + w1*b.w;
    *(float4*)&out[(size_t)s*DM + c4] = o;
}

// ---------------- zero-workspace fallback ----------------
__global__ __launch_bounds__(256) void fallback_kernel(const float* __restrict__ x, const float* __restrict__ Wg,
                                                       const float* __restrict__ W1, const float* __restrict__ b1,
                                                       const float* __restrict__ W2, const float* __restrict__ b2,
                                                       float* __restrict__ out){
    int s = blockIdx.x;
    int t = threadIdx.x;
    __shared__ float xr[DM];
    __shared__ float hl[DF];
    __shared__ float yl[DM];
    __shared__ float lacc[4*NE];
    __shared__ int   sel_e[2];
    __shared__ float sel_w[2];

    for (int i = t; i < DM; i += 256){ xr[i] = x[(size_t)s*DM + i]; yl[i] = 0.f; }
    __syncthreads();

    float acc[NE];
#pragma unroll
    for (int e = 0; e < NE; e++) acc[e] = 0.f;
    for (int d = t*3; d < t*3 + 3; d++){
        float xv = xr[d];
#pragma unroll
        for (int e = 0; e < NE; e++) acc[e] += xv * Wg[d*NE + e];
    }
#pragma unroll
    for (int e = 0; e < NE; e++){
#pragma unroll
        for (int off = 32; off; off >>= 1) acc[e] += __shfl_down(acc[e], off);
    }
    if ((t & 63) == 0){
        int wv = t >> 6;
#pragma unroll
        for (int e = 0; e < NE; e++) lacc[wv*NE + e] = acc[e];
    }
    __syncthreads();
    if (t == 0){
        float lg[NE];
#pragma unroll
        for (int e = 0; e < NE; e++) lg[e] = lacc[e] + lacc[NE + e] + lacc[2*NE + e] + lacc[3*NE + e];
        int i1 = 0; float v1 = lg[0];
        for (int e = 1; e < NE; e++) if (lg[e] > v1){ v1 = lg[e]; i1 = e; }
        int i2 = -1; float v2 = -1e30f;
        for (int e = 0; e < NE; e++) if (e != i1 && lg[e] > v2){ v2 = lg[e]; i2 = e; }
        if (i2 < 0){ i2 = (i1 + 1) & 7; sel_w[0] = 1.f; sel_w[1] = 0.f; }
        else {
            float e2 = expf(v2 - v1);
            sel_w[0] = 1.f / (1.f + e2);
            sel_w[1] = e2 / (1.f + e2);
        }
        sel_e[0] = i1; sel_e[1] = i2;
    }
    __syncthreads();

    for (int kk = 0; kk < 2; kk++){
        int e = sel_e[kk];
        float wgt = sel_w[kk];
        const float* w1p = W1 + (size_t)e * DM * DF;
        for (int j = t; j < DF; j += 256){
            float a = b1[e*DF + j];
            for (int k = 0; k < DM; k++) a += xr[k] * w1p[(size_t)k*DF + j];
            hl[j] = a > 0.f ? a : 0.f;
        }
        __syncthreads();
        const float* w2p = W2 + (size_t)e * DF * DM;
        for (int c = t; c < DM; c += 256){
            float a = b2[e*DM + c];
            for (int k = 0; k < DF; k++) a += hl[k] * w2p[(size_t)k*DM + c];
            yl[c] += wgt * a;
        }
        __syncthreads();
    }
    for (int c = t; c < DM; c += 256) out[(size_t)s*DM + c] = yl[c];
}

extern "C" void kernel_launch(void* const* d_in, const int* in_sizes, int n_in,
                              void* d_out, int out_size, void* d_ws, size_t ws_size,
                              hipStream_t stream) {
    const float* x  = (const float*)d_in[0];
    const float* Wg = (const float*)d_in[1];
    const float* W1 = (const float*)d_in[2];
    const float* b1 = (const float*)d_in[3];
    const float* W2 = (const float*)d_in[4];
    const float* b2 = (const float*)d_in[5];
    float* out = (float*)d_out;

    char* ws = (char*)d_ws;
    int*   counts = (int*)(ws + WS_COUNTS);
    int*   cursor = (int*)(ws + WS_CURSOR);
    int*   eid    = (int*)(ws + WS_EID);
    float* gw     = (float*)(ws + WS_GW);
    int*   pos_of = (int*)(ws + WS_POS);
    int*   tok_of = (int*)(ws + WS_TOK);

    const size_t xbB = (size_t)S_TOK*DM*2;           //  6.29 MB
    const size_t wB  = (size_t)NE*DM*DF*2;           // 37.75 MB each
    const size_t hB  = (size_t)PSLOT*DF*2;           // 56.62 MB
    const size_t need = CTRL_BYTES + xbB + 2*wB + hB;  // 138.7 MB

    if (ws_size < need){
        fallback_kernel<<<S_TOK, 256, 0, stream>>>(x, Wg, W1, b1, W2, b2, out);
        return;
    }

    u16* xb  = (u16*)(ws + CTRL_BYTES);
    u16* W1s = (u16*)(ws + CTRL_BYTES + xbB);
    u16* W2s = (u16*)(ws + CTRL_BYTES + xbB + wB);
    u16* h   = (u16*)(ws + CTRL_BYTES + xbB + 2*wB);
    // y (28.3 MB fp32) reuses the W1s region (37.75 MB) — W1s dead after gemm1.
    float* yb = (float*)(ws + CTRL_BYTES + xbB);

    cvtw_kernel<<<dim3(1152, NE), 256, 0, stream>>>(W1, W1s, W2, W2s, counts, cursor);
    gate_kernel<<<GATE_BLOCKS, 256, 0, stream>>>(x, Wg, eid, gw, counts, xb);
    scatter_kernel<<<PSLOT/256, 256, 0, stream>>>(eid, cursor, counts, tok_of, pos_of);

    gemm1p_kernel<<<24*TMAX*8, 256, 0, stream>>>(xb, tok_of, counts, W1s, b1, h);
    gemm2p_kernel<<<6*TMAX*8, 256, 0, stream>>>(h, counts, W2s, b2, yb);
    combine_kernel<<<(S_TOK*(DM/4))/256, 256, 0, stream>>>(yb, pos_of, gw, out);
}